// Round 12
// baseline (106.157 us; speedup 1.0000x reference)
//
#include <hip/hip_runtime.h>
#include <math.h>

// Problem constants (fixed by setup_inputs: B=8, H=W=64, C=256, sr=8)
static constexpr int Bb  = 8;
static constexpr int Nn  = 4096;   // H*W
static constexpr int Cc  = 256;
static constexpr int N1c = 256;    // 16x16 after 4x down
static constexpr int N2c = 64;     // 8x8 after 8x down

typedef __attribute__((ext_vector_type(8))) _Float16 f16x8;   // MFMA A/B frag
typedef __attribute__((ext_vector_type(4))) _Float16 f16x4;
typedef __attribute__((ext_vector_type(4))) float    f32x4v;  // MFMA acc

// =====================================================================================
// NODE 1: prep (weights->fp16) + fused dual downsample+LN+GELU.  Independent halves.
// blocks 0..255: weight cvt; blocks 256..767: down2 (b = t>>6, n2 = t&63).
// =====================================================================================
__global__ __launch_bounds__(256)
void prep_down(const float* __restrict__ w0, const float* __restrict__ w1,
               const float* __restrict__ w2, const float* __restrict__ w3,
               const float* __restrict__ x,
               const float* __restrict__ sr1w, const float* __restrict__ b1,
               const float* __restrict__ g1,   const float* __restrict__ lb1,
               const float* __restrict__ sr2w, const float* __restrict__ b2,
               const float* __restrict__ g2,   const float* __restrict__ lb2,
               _Float16* __restrict__ wf, _Float16* __restrict__ x1o,
               _Float16* __restrict__ x2o) {
  const int bid = blockIdx.x, c = threadIdx.x;
  if (bid < 256) {
    const int wsel = bid >> 6;
    const float* w = wsel == 0 ? w0 : wsel == 1 ? w1 : wsel == 2 ? w2 : w3;
    const int i = ((bid & 63) * 256 + c) * 4;
    float4 v = *(const float4*)(w + i);
    f16x4 o = {(_Float16)v.x, (_Float16)v.y, (_Float16)v.z, (_Float16)v.w};
    *(f16x4*)(wf + (size_t)wsel * 65536 + i) = o;
    return;
  }
  // ---------------- down2 ----------------
  const int t = bid - 256;
  const int b = t >> 6, n2 = t & 63;
  const int i2 = n2 >> 3, j2 = n2 & 7;
  const int lane = c & 63, wave = c >> 6;
  const float* xb = x + ((size_t)b * Nn) * Cc + c;

  float w1r[16];
#pragma unroll
  for (int q = 0; q < 4; ++q)
    *(float4*)&w1r[4 * q] = *(const float4*)(sr1w + c * 16 + 4 * q);

  float a2 = b2[c];
  float a1[2][2] = {{b1[c], b1[c]}, {b1[c], b1[c]}};
#pragma unroll
  for (int dy = 0; dy < 8; ++dy) {
    float vr[8], w2r[8];
    *(float4*)&w2r[0] = *(const float4*)(sr2w + c * 64 + dy * 8);
    *(float4*)&w2r[4] = *(const float4*)(sr2w + c * 64 + dy * 8 + 4);
#pragma unroll
    for (int dx = 0; dx < 8; ++dx)
      vr[dx] = xb[(size_t)((8 * i2 + dy) * 64 + 8 * j2 + dx) * 256];
#pragma unroll
    for (int dx = 0; dx < 8; ++dx) {
      a2 = fmaf(w2r[dx], vr[dx], a2);
      a1[dy >> 2][dx >> 2] = fmaf(w1r[(dy & 3) * 4 + (dx & 3)], vr[dx],
                                  a1[dy >> 2][dx >> 2]);
    }
  }
  float vals[5] = {a2, a1[0][0], a1[0][1], a1[1][0], a1[1][1]};
  __shared__ float redS[4][5], redQ[4][5];
#pragma unroll
  for (int p = 0; p < 5; ++p) {
    float s = vals[p], q2 = vals[p] * vals[p];
#pragma unroll
    for (int off = 1; off < 64; off <<= 1) {
      s  += __shfl_xor(s, off);
      q2 += __shfl_xor(q2, off);
    }
    if (lane == 0) { redS[wave][p] = s; redQ[wave][p] = q2; }
  }
  __syncthreads();
#pragma unroll
  for (int p = 0; p < 5; ++p) {
    const float sum = redS[0][p] + redS[1][p] + redS[2][p] + redS[3][p];
    const float sq  = redQ[0][p] + redQ[1][p] + redQ[2][p] + redQ[3][p];
    const float mean = sum * (1.f / Cc);
    const float var  = sq * (1.f / Cc) - mean * mean;
    const float gg = (p == 0) ? g2[c] : g1[c];
    const float bb = (p == 0) ? lb2[c] : lb1[c];
    const float xn = (vals[p] - mean) * rsqrtf(var + 1e-5f) * gg + bb;
    const float gel = 0.5f * xn * (1.f + erff(xn * 0.70710678118654752440f));
    if (p == 0) {
      x2o[((size_t)b * N2c + n2) * 256 + c] = (_Float16)gel;
    } else {
      const int a = (p - 1) >> 1, bbx = (p - 1) & 1;
      const int n1 = (2 * i2 + a) * 16 + (2 * j2 + bbx);
      x1o[((size_t)b * N1c + n1) * 256 + c] = (_Float16)gel;
    }
  }
}

// =====================================================================================
// GEMM body: LDS double-buffered fp16 MFMA. BM=64, BN=256(full), BK=32, 4 waves.
// AM: A mode  0=fp32 flat[.,256]  1=fp16 flat[.,256]  2=fp16 q-head-major [b][8][4096][32]
// OM: out     0=fp32 flat +bias   1=fp16 q-head-major  2=fp16 kv-head Ns=256  3=Ns=64
// Shared memory passed in (ONE allocation per kernel, not per instantiation).
// =====================================================================================
struct GemmSmem { _Float16 Asl[2][64][40]; _Float16 Bsl[2][256][40]; };

template<int AM, int OM, bool BIAS>
__device__ __forceinline__
void gemm_body(GemmSmem& sm, const void* __restrict__ Ain,
               const _Float16* __restrict__ Wf, const float* __restrict__ bias,
               void* __restrict__ Outv, int m0) {
  const int tid = threadIdx.x, lane = tid & 63, wid = tid >> 6;
  const int qi = lane & 15, g = lane >> 4;
  const int ar = tid >> 2, ak = (tid & 3) * 8;
  const int arow = m0 + ar;

  const float*    pa32 = (const float*)Ain + (size_t)arow * 256 + ak;
  const _Float16* pa16f = (const _Float16*)Ain + (size_t)arow * 256 + ak;
  const _Float16* pa16h = (const _Float16*)Ain
      + ((size_t)(arow >> 12) * 8 * 4096 + (arow & 4095)) * 32 + ak;
  const _Float16* pw = Wf + (size_t)tid * 256;

  f32x4v acc[4][4] = {};
  f16x8 rA; f16x8 rB[4];

#define LDREG(k0)                                                          \
  do {                                                                     \
    if (AM == 0) {                                                         \
      float4 t0 = *(const float4*)(pa32 + (k0));                           \
      float4 t1 = *(const float4*)(pa32 + (k0) + 4);                       \
      rA = (f16x8){(_Float16)t0.x, (_Float16)t0.y, (_Float16)t0.z,         \
                   (_Float16)t0.w, (_Float16)t1.x, (_Float16)t1.y,         \
                   (_Float16)t1.z, (_Float16)t1.w};                        \
    } else if (AM == 1) {                                                  \
      rA = *(const f16x8*)(pa16f + (k0));                                  \
    } else {                                                               \
      rA = *(const f16x8*)(pa16h + (size_t)((k0) >> 5) * 131072);          \
    }                                                                      \
    _Pragma("unroll")                                                      \
    for (int i = 0; i < 4; ++i) rB[i] = *(const f16x8*)(pw + (k0) + i * 8);\
  } while (0)

#define DSWRITE(buf)                                                       \
  do {                                                                     \
    *(f16x8*)&sm.Asl[buf][ar][ak] = rA;                                    \
    _Pragma("unroll")                                                      \
    for (int i = 0; i < 4; ++i) *(f16x8*)&sm.Bsl[buf][tid][i * 8] = rB[i]; \
  } while (0)

  LDREG(0);
  DSWRITE(0);
  LDREG(32);
  __syncthreads();

#pragma unroll
  for (int ks = 0; ks < 8; ++ks) {
    const int cur = ks & 1;
    if (ks < 7) DSWRITE(cur ^ 1);
    if (ks < 6) LDREG((ks + 2) * 32);
    f16x8 af[4], bf[4];
#pragma unroll
    for (int mt = 0; mt < 4; ++mt)
      af[mt] = *(const f16x8*)&sm.Asl[cur][mt * 16 + qi][g * 8];
#pragma unroll
    for (int nt = 0; nt < 4; ++nt)
      bf[nt] = *(const f16x8*)&sm.Bsl[cur][wid * 64 + nt * 16 + qi][g * 8];
#pragma unroll
    for (int nt = 0; nt < 4; ++nt)
#pragma unroll
      for (int mt = 0; mt < 4; ++mt)
        acc[mt][nt] = __builtin_amdgcn_mfma_f32_16x16x32_f16(af[mt], bf[nt], acc[mt][nt], 0, 0, 0);
    __syncthreads();
  }
#undef LDREG
#undef DSWRITE

#pragma unroll
  for (int nt = 0; nt < 4; ++nt) {
    const int col = wid * 64 + nt * 16 + qi;
    const float bv = BIAS ? bias[col] : 0.f;
    const int hs = col >> 5, d = col & 31;
#pragma unroll
    for (int mt = 0; mt < 4; ++mt) {
#pragma unroll
      for (int r = 0; r < 4; ++r) {
        const int row = m0 + mt * 16 + g * 4 + r;
        const float v = acc[mt][nt][r];
        if (OM == 0) {
          ((float*)Outv)[(size_t)row * 256 + col] = v + bv;
        } else if (OM == 1) {
          ((_Float16*)Outv)[((size_t)((row >> 12) * 8 + hs) * 4096 + (row & 4095)) * 32 + d] = (_Float16)v;
        } else if (OM == 2) {
          ((_Float16*)Outv)[((size_t)((row >> 8) * 8 + hs) * 256 + (row & 255)) * 32 + d] = (_Float16)v;
        } else {
          ((_Float16*)Outv)[((size_t)((row >> 6) * 8 + hs) * 64 + (row & 63)) * 32 + d] = (_Float16)v;
        }
      }
    }
  }
}

// NODE 2: q projection (512 blocks) + kv1 (32) + kv2 (8)
__global__ __launch_bounds__(256)
void gemms_qkv(const float* __restrict__ x, const _Float16* __restrict__ x1h,
               const _Float16* __restrict__ x2h, const _Float16* __restrict__ wf,
               _Float16* __restrict__ qh, _Float16* __restrict__ kv1,
               _Float16* __restrict__ kv2) {
  __shared__ GemmSmem sm;
  const int bx = blockIdx.x;
  if (bx < 512)      gemm_body<0, 1, false>(sm, x,   wf,             nullptr, qh,  bx * 64);
  else if (bx < 544) gemm_body<1, 2, false>(sm, x1h, wf + 65536,     nullptr, kv1, (bx - 512) * 64);
  else               gemm_body<1, 3, false>(sm, x2h, wf + 2 * 65536, nullptr, kv2, (bx - 544) * 64);
}

// NODE 4: output projection + bias (A = fp16 head-major, out fp32)
__global__ __launch_bounds__(256)
void gemm_proj(const _Float16* __restrict__ qh, const _Float16* __restrict__ wf,
               const float* __restrict__ bias, float* __restrict__ out) {
  __shared__ GemmSmem sm;
  gemm_body<2, 0, true>(sm, qh, wf, bias, out, blockIdx.x * 64);
}

// =====================================================================================
// NODE 3: attention with in-kernel depthwise 3x3 vconv.
// Layouts: qh [b][8][4096][32] (hg = br*4+h; in-place q->o). kv [b][8][NS][32]
// (slices 0..3 = K heads, 4..7 = V heads). All staging loads fully coalesced.
// =====================================================================================
template<int NS, int HS>
__device__ __forceinline__
void attn_body(char* smem, _Float16* __restrict__ qh, const _Float16* __restrict__ kvh,
               const float* __restrict__ lcw, const float* __restrict__ lcb,
               int qc, int b, int h, int hg) {
  constexpr int NT = NS / 16, NC = NS / 32, PS = NS + 8;
  constexpr float KC = 0.17677669529663688f * 1.4426950408889634f; // scale*log2e
  _Float16 (*Klds)[40] = (_Float16(*)[40])smem;
  _Float16 (*Vt)[PS]   = (_Float16(*)[PS])(smem + (size_t)NS * 40 * 2);
  _Float16* PlBase     = (_Float16*)(smem + (size_t)NS * 40 * 2 + (size_t)32 * PS * 2);
  _Float16 (*vraw)[32] = (_Float16(*)[32])PlBase;   // union: vraw dead before Pl use

  const int tid = threadIdx.x, lane = tid & 63, wid = tid >> 6;
  const int g = lane >> 4, qi = lane & 15;

  // ---- stage K rows + raw V rows (64B contiguous per row -> coalesced) ----
  const _Float16* kp0 = kvh + ((size_t)(b * 8 + h) * NS) * 32;
  const _Float16* vp0 = kvh + ((size_t)(b * 8 + 4 + h) * NS) * 32;
  for (int r = tid; r < NS; r += 256) {
#pragma unroll
    for (int i = 0; i < 4; ++i)
      *(f16x8*)&Klds[r][8 * i] = *(const f16x8*)(kp0 + (size_t)r * 32 + 8 * i);
#pragma unroll
    for (int i = 0; i < 4; ++i)
      *(f16x8*)&vraw[r][8 * i] = *(const f16x8*)(vp0 + (size_t)r * 32 + 8 * i);
  }
  __syncthreads();

  // ---- depthwise 3x3 conv (zero-pad) fused: Vt[d][r] = vraw + bias + conv ----
  {
    const int d = tid & 31, rg = tid >> 5;
    const int cc = h * 32 + d;
    float wreg[9];
#pragma unroll
    for (int q = 0; q < 9; ++q) wreg[q] = lcw[cc * 9 + q];
    const float bv = lcb[cc];
    for (int r0 = rg; r0 < NS; r0 += 8) {
      const int i = r0 / HS, j = r0 % HS;
      float acc = bv;
#pragma unroll
      for (int dy = 0; dy < 3; ++dy) {
        const int ii = i + dy - 1;
        if (ii < 0 || ii >= HS) continue;
#pragma unroll
        for (int dx = 0; dx < 3; ++dx) {
          const int jj = j + dx - 1;
          if (jj < 0 || jj >= HS) continue;
          acc = fmaf(wreg[dy * 3 + dx], (float)vraw[ii * HS + jj][d], acc);
        }
      }
      Vt[d][r0] = (_Float16)((float)vraw[r0][d] + acc);
    }
  }
  __syncthreads();   // vraw dead; its space becomes Pl

  // ---- V^T A-frags from LDS ----
  f16x8 vt[2][NC];
#pragma unroll
  for (int dt = 0; dt < 2; ++dt)
#pragma unroll
    for (int c = 0; c < NC; ++c)
      vt[dt][c] = *(const f16x8*)&Vt[16 * dt + qi][32 * c + 8 * g];

  _Float16* Pw = PlBase + (size_t)(wid * 16 + qi) * PS;
  _Float16* qbase = qh + ((size_t)(b * 8 + hg) * 4096) * 32;

  for (int qt = 0; qt < 4; ++qt) {
    const int qrow = qc * 256 + wid * 64 + qt * 16 + qi;
    _Float16* qp = qbase + (size_t)qrow * 32;
    f16x8 qfrag = *(const f16x8*)(qp + 8 * g);
    f32x4v s[NT];
#pragma unroll
    for (int t = 0; t < NT; ++t) {
      f16x8 kf = *(const f16x8*)&Klds[16 * t + qi][8 * g];
      s[t] = __builtin_amdgcn_mfma_f32_16x16x32_f16(kf, qfrag,
                                                    (f32x4v){0.f, 0.f, 0.f, 0.f}, 0, 0, 0);
    }
    float m = s[0][0];
#pragma unroll
    for (int t = 0; t < NT; ++t)
      m = fmaxf(m, fmaxf(fmaxf(s[t][0], s[t][1]), fmaxf(s[t][2], s[t][3])));
    m = fmaxf(m, __shfl_xor(m, 16));
    m = fmaxf(m, __shfl_xor(m, 32));
    float l = 0.f;
#pragma unroll
    for (int t = 0; t < NT; ++t)
#pragma unroll
      for (int r = 0; r < 4; ++r) {
        float p = exp2f((s[t][r] - m) * KC);
        s[t][r] = p; l += p;
      }
    l += __shfl_xor(l, 16);
    l += __shfl_xor(l, 32);
#pragma unroll
    for (int t = 0; t < NT; ++t) {
      f16x4 pw = {(_Float16)s[t][0], (_Float16)s[t][1],
                  (_Float16)s[t][2], (_Float16)s[t][3]};
      *(f16x4*)&Pw[16 * t + 4 * g] = pw;
    }
    f32x4v o0 = {0.f, 0.f, 0.f, 0.f}, o1 = {0.f, 0.f, 0.f, 0.f};
#pragma unroll
    for (int c = 0; c < NC; ++c) {
      f16x8 pf = *(const f16x8*)&Pw[32 * c + 8 * g];
      o0 = __builtin_amdgcn_mfma_f32_16x16x32_f16(vt[0][c], pf, o0, 0, 0, 0);
      o1 = __builtin_amdgcn_mfma_f32_16x16x32_f16(vt[1][c], pf, o1, 0, 0, 0);
    }
    const float inv = 1.f / l;
    f16x4 O0 = {(_Float16)(o0[0] * inv), (_Float16)(o0[1] * inv),
                (_Float16)(o0[2] * inv), (_Float16)(o0[3] * inv)};
    f16x4 O1 = {(_Float16)(o1[0] * inv), (_Float16)(o1[1] * inv),
                (_Float16)(o1[2] * inv), (_Float16)(o1[3] * inv)};
    *(f16x4*)(qp + 4 * g)      = O0;
    *(f16x4*)(qp + 16 + 4 * g) = O1;
  }
}

__global__ __launch_bounds__(256, 2)
void attn_all(_Float16* __restrict__ qh,
              const _Float16* __restrict__ kv1, const _Float16* __restrict__ kv2,
              const float* __restrict__ lc1w, const float* __restrict__ lc1b,
              const float* __restrict__ lc2w, const float* __restrict__ lc2b) {
  __shared__ __align__(16) char smem[71168];   // K(20480) + Vt(16896) + Pl(33792)
  const int z = blockIdx.z;
  const int b = z >> 1, br = z & 1;
  const int h = blockIdx.y;
  if (br == 0) attn_body<256, 16>(smem, qh, kv1, lc1w, lc1b, blockIdx.x, b, h, h);
  else         attn_body<64,  8>(smem, qh, kv2, lc2w, lc2b, blockIdx.x, b, h, 4 + h);
}

extern "C" void kernel_launch(void* const* d_in, const int* in_sizes, int n_in,
                              void* d_out, int out_size, void* d_ws, size_t ws_size,
                              hipStream_t stream) {
  const float* x      = (const float*)d_in[0];
  const float* q_w    = (const float*)d_in[1];
  const float* kv1_w  = (const float*)d_in[2];
  const float* kv2_w  = (const float*)d_in[3];
  const float* proj_w = (const float*)d_in[4];
  const float* proj_b = (const float*)d_in[5];
  const float* sr1_w  = (const float*)d_in[6];
  const float* sr1_b  = (const float*)d_in[7];
  const float* sr2_w  = (const float*)d_in[8];
  const float* sr2_b  = (const float*)d_in[9];
  const float* ln1_g  = (const float*)d_in[10];
  const float* ln1_b  = (const float*)d_in[11];
  const float* ln2_g  = (const float*)d_in[12];
  const float* ln2_b  = (const float*)d_in[13];
  const float* lc1_w  = (const float*)d_in[14];
  const float* lc1_b  = (const float*)d_in[15];
  const float* lc2_w  = (const float*)d_in[16];
  const float* lc2_b  = (const float*)d_in[17];
  float* out = (float*)d_out;

  // workspace layout (fp16 units)
  _Float16* wf   = (_Float16*)d_ws;                      // [4][65536]
  _Float16* qh   = wf + (size_t)4 * 65536;               // [B][8][4096][32]
  _Float16* x1h  = qh + (size_t)Bb * Nn * Cc;            // [B*256][256]
  _Float16* x2h  = x1h + (size_t)Bb * N1c * Cc;          // [B*64][256]
  _Float16* kv1h = x2h + (size_t)Bb * N2c * Cc;          // [B][8][256][32]
  _Float16* kv2h = kv1h + (size_t)Bb * N1c * Cc;         // [B][8][64][32]

  // NODE 1: weights->fp16 + fused downsample/LN/GELU (x read once)
  prep_down<<<768, 256, 0, stream>>>(q_w, kv1_w, kv2_w, proj_w, x,
                                     sr1_w, sr1_b, ln1_g, ln1_b,
                                     sr2_w, sr2_b, ln2_g, ln2_b,
                                     wf, x1h, x2h);
  // NODE 2: q projection + kv projections (head-major fp16 outputs)
  gemms_qkv<<<552, 256, 0, stream>>>(x, x1h, x2h, wf, qh, kv1h, kv2h);
  // NODE 3: attention (vconv fused; in-place q -> o in qh)
  attn_all<<<dim3(16, 4, 16), 256, 0, stream>>>(qh, kv1h, kv2h,
                                                lc1_w, lc1_b, lc2_w, lc2_b);
  // NODE 4: output projection + bias
  gemm_proj<<<512, 256, 0, stream>>>(qh, wf + 3 * 65536, proj_b, out);
}

// Round 13
// 88.459 us; speedup vs baseline: 1.2001x; 1.2001x over previous
//
#include <hip/hip_runtime.h>
#include <math.h>

// Problem constants (fixed by setup_inputs: B=8, H=W=64, C=256, sr=8)
static constexpr int Bb  = 8;
static constexpr int Nn  = 4096;   // H*W
static constexpr int Cc  = 256;
static constexpr int N1c = 256;    // 16x16 after 4x down
static constexpr int N2c = 64;     // 8x8 after 8x down

typedef __attribute__((ext_vector_type(8))) _Float16 f16x8;   // MFMA A/B frag
typedef __attribute__((ext_vector_type(4))) _Float16 f16x4;
typedef __attribute__((ext_vector_type(4))) float    f32x4v;  // MFMA acc

// =====================================================================================
// NODE 1: prep (weights->fp16) + fused dual downsample+LN+GELU.  Independent halves.
// blocks 0..255: weight cvt; blocks 256..767: down2 (b = t>>6, n2 = t&63).
// =====================================================================================
__global__ __launch_bounds__(256)
void prep_down(const float* __restrict__ w0, const float* __restrict__ w1,
               const float* __restrict__ w2, const float* __restrict__ w3,
               const float* __restrict__ x,
               const float* __restrict__ sr1w, const float* __restrict__ b1,
               const float* __restrict__ g1,   const float* __restrict__ lb1,
               const float* __restrict__ sr2w, const float* __restrict__ b2,
               const float* __restrict__ g2,   const float* __restrict__ lb2,
               _Float16* __restrict__ wf, _Float16* __restrict__ x1o,
               _Float16* __restrict__ x2o) {
  const int bid = blockIdx.x, c = threadIdx.x;
  if (bid < 256) {
    const int wsel = bid >> 6;
    const float* w = wsel == 0 ? w0 : wsel == 1 ? w1 : wsel == 2 ? w2 : w3;
    const int i = ((bid & 63) * 256 + c) * 4;
    float4 v = *(const float4*)(w + i);
    f16x4 o = {(_Float16)v.x, (_Float16)v.y, (_Float16)v.z, (_Float16)v.w};
    *(f16x4*)(wf + (size_t)wsel * 65536 + i) = o;
    return;
  }
  // ---------------- down2 ----------------
  const int t = bid - 256;
  const int b = t >> 6, n2 = t & 63;
  const int i2 = n2 >> 3, j2 = n2 & 7;
  const int lane = c & 63, wave = c >> 6;
  const float* xb = x + ((size_t)b * Nn) * Cc + c;

  float w1r[16];
#pragma unroll
  for (int q = 0; q < 4; ++q)
    *(float4*)&w1r[4 * q] = *(const float4*)(sr1w + c * 16 + 4 * q);

  float a2 = b2[c];
  float a1[2][2] = {{b1[c], b1[c]}, {b1[c], b1[c]}};
#pragma unroll
  for (int dy = 0; dy < 8; ++dy) {
    float vr[8], w2r[8];
    *(float4*)&w2r[0] = *(const float4*)(sr2w + c * 64 + dy * 8);
    *(float4*)&w2r[4] = *(const float4*)(sr2w + c * 64 + dy * 8 + 4);
#pragma unroll
    for (int dx = 0; dx < 8; ++dx)
      vr[dx] = xb[(size_t)((8 * i2 + dy) * 64 + 8 * j2 + dx) * 256];
#pragma unroll
    for (int dx = 0; dx < 8; ++dx) {
      a2 = fmaf(w2r[dx], vr[dx], a2);
      a1[dy >> 2][dx >> 2] = fmaf(w1r[(dy & 3) * 4 + (dx & 3)], vr[dx],
                                  a1[dy >> 2][dx >> 2]);
    }
  }
  float vals[5] = {a2, a1[0][0], a1[0][1], a1[1][0], a1[1][1]};
  __shared__ float redS[4][5], redQ[4][5];
#pragma unroll
  for (int p = 0; p < 5; ++p) {
    float s = vals[p], q2 = vals[p] * vals[p];
#pragma unroll
    for (int off = 1; off < 64; off <<= 1) {
      s  += __shfl_xor(s, off);
      q2 += __shfl_xor(q2, off);
    }
    if (lane == 0) { redS[wave][p] = s; redQ[wave][p] = q2; }
  }
  __syncthreads();
#pragma unroll
  for (int p = 0; p < 5; ++p) {
    const float sum = redS[0][p] + redS[1][p] + redS[2][p] + redS[3][p];
    const float sq  = redQ[0][p] + redQ[1][p] + redQ[2][p] + redQ[3][p];
    const float mean = sum * (1.f / Cc);
    const float var  = sq * (1.f / Cc) - mean * mean;
    const float gg = (p == 0) ? g2[c] : g1[c];
    const float bb = (p == 0) ? lb2[c] : lb1[c];
    const float xn = (vals[p] - mean) * rsqrtf(var + 1e-5f) * gg + bb;
    const float gel = 0.5f * xn * (1.f + erff(xn * 0.70710678118654752440f));
    if (p == 0) {
      x2o[((size_t)b * N2c + n2) * 256 + c] = (_Float16)gel;
    } else {
      const int a = (p - 1) >> 1, bbx = (p - 1) & 1;
      const int n1 = (2 * i2 + a) * 16 + (2 * j2 + bbx);
      x1o[((size_t)b * N1c + n1) * 256 + c] = (_Float16)gel;
    }
  }
}

// =====================================================================================
// GEMM body: LDS double-buffered fp16 MFMA. BM=64, BN=256(full), BK=32, 4 waves.
// AM: A mode  0=fp32 flat[.,256]  1=fp16 flat[.,256]  2=fp16 q-head-major [b][8][4096][32]
// OM: out     0=fp32 flat +bias   1=fp16 q-head-major  2=fp16 kv-head Ns=256  3=Ns=64
// =====================================================================================
struct GemmSmem { _Float16 Asl[2][64][40]; _Float16 Bsl[2][256][40]; };

template<int AM, int OM, bool BIAS>
__device__ __forceinline__
void gemm_body(GemmSmem& sm, const void* __restrict__ Ain,
               const _Float16* __restrict__ Wf, const float* __restrict__ bias,
               void* __restrict__ Outv, int m0) {
  const int tid = threadIdx.x, lane = tid & 63, wid = tid >> 6;
  const int qi = lane & 15, g = lane >> 4;
  const int ar = tid >> 2, ak = (tid & 3) * 8;
  const int arow = m0 + ar;

  const float*    pa32 = (const float*)Ain + (size_t)arow * 256 + ak;
  const _Float16* pa16f = (const _Float16*)Ain + (size_t)arow * 256 + ak;
  const _Float16* pa16h = (const _Float16*)Ain
      + ((size_t)(arow >> 12) * 8 * 4096 + (arow & 4095)) * 32 + ak;
  const _Float16* pw = Wf + (size_t)tid * 256;

  f32x4v acc[4][4] = {};
  f16x8 rA; f16x8 rB[4];

#define LDREG(k0)                                                          \
  do {                                                                     \
    if (AM == 0) {                                                         \
      float4 t0 = *(const float4*)(pa32 + (k0));                           \
      float4 t1 = *(const float4*)(pa32 + (k0) + 4);                       \
      rA = (f16x8){(_Float16)t0.x, (_Float16)t0.y, (_Float16)t0.z,         \
                   (_Float16)t0.w, (_Float16)t1.x, (_Float16)t1.y,         \
                   (_Float16)t1.z, (_Float16)t1.w};                        \
    } else if (AM == 1) {                                                  \
      rA = *(const f16x8*)(pa16f + (k0));                                  \
    } else {                                                               \
      rA = *(const f16x8*)(pa16h + (size_t)((k0) >> 5) * 131072);          \
    }                                                                      \
    _Pragma("unroll")                                                      \
    for (int i = 0; i < 4; ++i) rB[i] = *(const f16x8*)(pw + (k0) + i * 8);\
  } while (0)

#define DSWRITE(buf)                                                       \
  do {                                                                     \
    *(f16x8*)&sm.Asl[buf][ar][ak] = rA;                                    \
    _Pragma("unroll")                                                      \
    for (int i = 0; i < 4; ++i) *(f16x8*)&sm.Bsl[buf][tid][i * 8] = rB[i]; \
  } while (0)

  LDREG(0);
  DSWRITE(0);
  LDREG(32);
  __syncthreads();

#pragma unroll
  for (int ks = 0; ks < 8; ++ks) {
    const int cur = ks & 1;
    if (ks < 7) DSWRITE(cur ^ 1);
    if (ks < 6) LDREG((ks + 2) * 32);
    f16x8 af[4], bf[4];
#pragma unroll
    for (int mt = 0; mt < 4; ++mt)
      af[mt] = *(const f16x8*)&sm.Asl[cur][mt * 16 + qi][g * 8];
#pragma unroll
    for (int nt = 0; nt < 4; ++nt)
      bf[nt] = *(const f16x8*)&sm.Bsl[cur][wid * 64 + nt * 16 + qi][g * 8];
#pragma unroll
    for (int nt = 0; nt < 4; ++nt)
#pragma unroll
      for (int mt = 0; mt < 4; ++mt)
        acc[mt][nt] = __builtin_amdgcn_mfma_f32_16x16x32_f16(af[mt], bf[nt], acc[mt][nt], 0, 0, 0);
    __syncthreads();
  }
#undef LDREG
#undef DSWRITE

#pragma unroll
  for (int nt = 0; nt < 4; ++nt) {
    const int col = wid * 64 + nt * 16 + qi;
    const float bv = BIAS ? bias[col] : 0.f;
    const int hs = col >> 5, d = col & 31;
#pragma unroll
    for (int mt = 0; mt < 4; ++mt) {
#pragma unroll
      for (int r = 0; r < 4; ++r) {
        const int row = m0 + mt * 16 + g * 4 + r;
        const float v = acc[mt][nt][r];
        if (OM == 0) {
          ((float*)Outv)[(size_t)row * 256 + col] = v + bv;
        } else if (OM == 1) {
          ((_Float16*)Outv)[((size_t)((row >> 12) * 8 + hs) * 4096 + (row & 4095)) * 32 + d] = (_Float16)v;
        } else if (OM == 2) {
          ((_Float16*)Outv)[((size_t)((row >> 8) * 8 + hs) * 256 + (row & 255)) * 32 + d] = (_Float16)v;
        } else {
          ((_Float16*)Outv)[((size_t)((row >> 6) * 8 + hs) * 64 + (row & 63)) * 32 + d] = (_Float16)v;
        }
      }
    }
  }
}

// NODE 2: q projection (512 blocks) + kv1 (32) + kv2 (8)
__global__ __launch_bounds__(256)
void gemms_qkv(const float* __restrict__ x, const _Float16* __restrict__ x1h,
               const _Float16* __restrict__ x2h, const _Float16* __restrict__ wf,
               _Float16* __restrict__ qh, _Float16* __restrict__ kv1,
               _Float16* __restrict__ kv2) {
  __shared__ GemmSmem sm;
  const int bx = blockIdx.x;
  if (bx < 512)      gemm_body<0, 1, false>(sm, x,   wf,             nullptr, qh,  bx * 64);
  else if (bx < 544) gemm_body<1, 2, false>(sm, x1h, wf + 65536,     nullptr, kv1, (bx - 512) * 64);
  else               gemm_body<1, 3, false>(sm, x2h, wf + 2 * 65536, nullptr, kv2, (bx - 544) * 64);
}

// NODE 4: output projection + bias (A = fp16 head-major, out fp32)
__global__ __launch_bounds__(256)
void gemm_proj(const _Float16* __restrict__ qh, const _Float16* __restrict__ wf,
               const float* __restrict__ bias, float* __restrict__ out) {
  __shared__ GemmSmem sm;
  gemm_body<2, 0, true>(sm, qh, wf, bias, out, blockIdx.x * 64);
}

// =====================================================================================
// NODE 2.5: depthwise 3x3 conv on V, output TRANSPOSED global [b][4][32][NS].
// vnew^T[d][r] = v[r][d] + bias[d] + sum conv. Thread = (row r, 8-channel slice dp).
// All neighbor reads coalesced f16x8 from L2-hot kv; per-d writes are 32B segments.
// Computed ONCE per (b,h) — this was 16x-redundant inside attn in the prior round.
// =====================================================================================
template<int NS, int HS>
__device__ __forceinline__
void vconvt_body(const _Float16* __restrict__ kvh, const float* __restrict__ lcw,
                 const float* __restrict__ lcb, _Float16* __restrict__ vtg,
                 int b, int h, int rbase) {
  const int tid = threadIdx.x;
  const int r = rbase + (tid >> 2), dp = tid & 3, d0 = dp * 8;
  const int i = r / HS, j = r % HS;
  const _Float16* vsrc = kvh + ((size_t)(b * 8 + 4 + h) * NS) * 32;
  const float* wb = lcw + (h * 32 + d0) * 9;   // per-channel [9] taps, row-major
  float acc[8];
#pragma unroll
  for (int e = 0; e < 8; ++e) acc[e] = lcb[h * 32 + d0 + e];
#pragma unroll
  for (int dy = 0; dy < 3; ++dy) {
    const int ii = i + dy - 1;
    if (ii < 0 || ii >= HS) continue;
#pragma unroll
    for (int dx = 0; dx < 3; ++dx) {
      const int jj = j + dx - 1;
      if (jj < 0 || jj >= HS) continue;
      f16x8 v = *(const f16x8*)(vsrc + (size_t)(ii * HS + jj) * 32 + d0);
#pragma unroll
      for (int e = 0; e < 8; ++e)
        acc[e] = fmaf(wb[e * 9 + dy * 3 + dx], (float)v[e], acc[e]);
    }
  }
  f16x8 self = *(const f16x8*)(vsrc + (size_t)r * 32 + d0);
  _Float16* dst = vtg + ((size_t)(b * 4 + h) * 32 + d0) * NS + r;
#pragma unroll
  for (int e = 0; e < 8; ++e)
    dst[(size_t)e * NS] = (_Float16)(acc[e] + (float)self[e]);
}

__global__ __launch_bounds__(256)
void vconv_t(const _Float16* __restrict__ kv1, const _Float16* __restrict__ kv2,
             const float* __restrict__ lc1w, const float* __restrict__ lc1b,
             const float* __restrict__ lc2w, const float* __restrict__ lc2b,
             _Float16* __restrict__ vt1, _Float16* __restrict__ vt2) {
  const int bid = blockIdx.x;
  if (bid < 128) {   // branch1: 32 (b,h) x 4 row-chunks of 64
    const int b = bid >> 4, h = (bid >> 2) & 3, rc = bid & 3;
    vconvt_body<256, 16>(kv1, lc1w, lc1b, vt1, b, h, rc * 64);
  } else {           // branch2: 32 (b,h), 64 rows each
    const int t = bid - 128;
    vconvt_body<64, 8>(kv2, lc2w, lc2b, vt2, t >> 2, t & 3, 0);
  }
}

// =====================================================================================
// NODE 3: attention. K from kv [b][8][NS][32] (slices 0..3); V^T pre-convolved from
// vt [b][4][32][NS]. V-frags hoisted to registers; Vt LDS region reused as Pl.
// LDS = 20480 (Klds) + 33792 (union Vt/Pl) = 54272 -> 3 blocks/CU.
// =====================================================================================
template<int NS, int HS>
__device__ __forceinline__
void attn_body(char* smem, _Float16* __restrict__ qh, const _Float16* __restrict__ kvh,
               const _Float16* __restrict__ vtg, int qc, int b, int h, int hg) {
  constexpr int NT = NS / 16, NC = NS / 32, PS = NS + 8;
  constexpr float KC = 0.17677669529663688f * 1.4426950408889634f; // scale*log2e
  _Float16 (*Klds)[40] = (_Float16(*)[40])smem;
  char* ubase = smem + (size_t)NS * 40 * 2;
  _Float16 (*Vt)[PS]  = (_Float16(*)[PS])ubase;   // staging; dead after frag hoist
  _Float16* PlBase    = (_Float16*)ubase;         // reuses Vt region

  const int tid = threadIdx.x, lane = tid & 63, wid = tid >> 6;
  const int g = lane >> 4, qi = lane & 15;

  // ---- stage K rows (coalesced) + Vt rows (coalesced, already transposed) ----
  const _Float16* kp0 = kvh + ((size_t)(b * 8 + h) * NS) * 32;
  for (int r = tid; r < NS; r += 256) {
#pragma unroll
    for (int i = 0; i < 4; ++i)
      *(f16x8*)&Klds[r][8 * i] = *(const f16x8*)(kp0 + (size_t)r * 32 + 8 * i);
  }
  {
    const _Float16* vg = vtg + ((size_t)(b * 4 + h) * 32) * NS;
    constexpr int CPR = NS / 8;   // f16x8 chunks per Vt row
    for (int u = tid; u < 32 * CPR; u += 256) {
      const int d = u / CPR, cj = u % CPR;
      *(f16x8*)&Vt[d][cj * 8] = *(const f16x8*)(vg + (size_t)d * NS + cj * 8);
    }
  }
  __syncthreads();

  // ---- hoist V^T A-frags to registers ----
  f16x8 vt[2][NC];
#pragma unroll
  for (int dt = 0; dt < 2; ++dt)
#pragma unroll
    for (int c = 0; c < NC; ++c)
      vt[dt][c] = *(const f16x8*)&Vt[16 * dt + qi][32 * c + 8 * g];
  __syncthreads();   // Vt dead; region becomes Pl

  _Float16* Pw = PlBase + (size_t)(wid * 16 + qi) * PS;
  _Float16* qbase = qh + ((size_t)(b * 8 + hg) * 4096) * 32;

  for (int qt = 0; qt < 4; ++qt) {
    const int qrow = qc * 256 + wid * 64 + qt * 16 + qi;
    _Float16* qp = qbase + (size_t)qrow * 32;
    f16x8 qfrag = *(const f16x8*)(qp + 8 * g);
    f32x4v s[NT];
#pragma unroll
    for (int t = 0; t < NT; ++t) {
      f16x8 kf = *(const f16x8*)&Klds[16 * t + qi][8 * g];
      s[t] = __builtin_amdgcn_mfma_f32_16x16x32_f16(kf, qfrag,
                                                    (f32x4v){0.f, 0.f, 0.f, 0.f}, 0, 0, 0);
    }
    float m = s[0][0];
#pragma unroll
    for (int t = 0; t < NT; ++t)
      m = fmaxf(m, fmaxf(fmaxf(s[t][0], s[t][1]), fmaxf(s[t][2], s[t][3])));
    m = fmaxf(m, __shfl_xor(m, 16));
    m = fmaxf(m, __shfl_xor(m, 32));
    float l = 0.f;
#pragma unroll
    for (int t = 0; t < NT; ++t)
#pragma unroll
      for (int r = 0; r < 4; ++r) {
        float p = exp2f((s[t][r] - m) * KC);
        s[t][r] = p; l += p;
      }
    l += __shfl_xor(l, 16);
    l += __shfl_xor(l, 32);
#pragma unroll
    for (int t = 0; t < NT; ++t) {
      f16x4 pw = {(_Float16)s[t][0], (_Float16)s[t][1],
                  (_Float16)s[t][2], (_Float16)s[t][3]};
      *(f16x4*)&Pw[16 * t + 4 * g] = pw;
    }
    f32x4v o0 = {0.f, 0.f, 0.f, 0.f}, o1 = {0.f, 0.f, 0.f, 0.f};
#pragma unroll
    for (int c = 0; c < NC; ++c) {
      f16x8 pf = *(const f16x8*)&Pw[32 * c + 8 * g];
      o0 = __builtin_amdgcn_mfma_f32_16x16x32_f16(vt[0][c], pf, o0, 0, 0, 0);
      o1 = __builtin_amdgcn_mfma_f32_16x16x32_f16(vt[1][c], pf, o1, 0, 0, 0);
    }
    const float inv = 1.f / l;
    f16x4 O0 = {(_Float16)(o0[0] * inv), (_Float16)(o0[1] * inv),
                (_Float16)(o0[2] * inv), (_Float16)(o0[3] * inv)};
    f16x4 O1 = {(_Float16)(o1[0] * inv), (_Float16)(o1[1] * inv),
                (_Float16)(o1[2] * inv), (_Float16)(o1[3] * inv)};
    *(f16x4*)(qp + 4 * g)      = O0;
    *(f16x4*)(qp + 16 + 4 * g) = O1;
  }
}

__global__ __launch_bounds__(256, 3)
void attn_all(_Float16* __restrict__ qh,
              const _Float16* __restrict__ kv1, const _Float16* __restrict__ kv2,
              const _Float16* __restrict__ vt1, const _Float16* __restrict__ vt2) {
  __shared__ __align__(16) char smem[54272];   // Klds(20480) + union{Vt, Pl}(33792)
  const int z = blockIdx.z;
  const int b = z >> 1, br = z & 1;
  const int h = blockIdx.y;
  if (br == 0) attn_body<256, 16>(smem, qh, kv1, vt1, blockIdx.x, b, h, h);
  else         attn_body<64,  8>(smem, qh, kv2, vt2, blockIdx.x, b, h, 4 + h);
}

extern "C" void kernel_launch(void* const* d_in, const int* in_sizes, int n_in,
                              void* d_out, int out_size, void* d_ws, size_t ws_size,
                              hipStream_t stream) {
  const float* x      = (const float*)d_in[0];
  const float* q_w    = (const float*)d_in[1];
  const float* kv1_w  = (const float*)d_in[2];
  const float* kv2_w  = (const float*)d_in[3];
  const float* proj_w = (const float*)d_in[4];
  const float* proj_b = (const float*)d_in[5];
  const float* sr1_w  = (const float*)d_in[6];
  const float* sr1_b  = (const float*)d_in[7];
  const float* sr2_w  = (const float*)d_in[8];
  const float* sr2_b  = (const float*)d_in[9];
  const float* ln1_g  = (const float*)d_in[10];
  const float* ln1_b  = (const float*)d_in[11];
  const float* ln2_g  = (const float*)d_in[12];
  const float* ln2_b  = (const float*)d_in[13];
  const float* lc1_w  = (const float*)d_in[14];
  const float* lc1_b  = (const float*)d_in[15];
  const float* lc2_w  = (const float*)d_in[16];
  const float* lc2_b  = (const float*)d_in[17];
  float* out = (float*)d_out;

  // workspace layout (fp16 units)
  _Float16* wf   = (_Float16*)d_ws;                      // [4][65536]
  _Float16* qh   = wf + (size_t)4 * 65536;               // [B][8][4096][32]
  _Float16* x1h  = qh + (size_t)Bb * Nn * Cc;            // [B*256][256]
  _Float16* x2h  = x1h + (size_t)Bb * N1c * Cc;          // [B*64][256]
  _Float16* kv1h = x2h + (size_t)Bb * N2c * Cc;          // [B][8][256][32]
  _Float16* kv2h = kv1h + (size_t)Bb * N1c * Cc;         // [B][8][64][32]
  _Float16* vt1  = kv2h + (size_t)Bb * N2c * Cc;         // [B][4][32][256]
  _Float16* vt2  = vt1  + (size_t)Bb * 4 * 32 * N1c;     // [B][4][32][64]

  // NODE 1: weights->fp16 + fused downsample/LN/GELU (x read once)
  prep_down<<<768, 256, 0, stream>>>(q_w, kv1_w, kv2_w, proj_w, x,
                                     sr1_w, sr1_b, ln1_g, ln1_b,
                                     sr2_w, sr2_b, ln2_g, ln2_b,
                                     wf, x1h, x2h);
  // NODE 2: q projection + kv projections (head-major fp16 outputs)
  gemms_qkv<<<552, 256, 0, stream>>>(x, x1h, x2h, wf, qh, kv1h, kv2h);
  // NODE 2.5: depthwise conv -> transposed V (once per (b,h))
  vconv_t<<<160, 256, 0, stream>>>(kv1h, kv2h, lc1_w, lc1_b, lc2_w, lc2_b, vt1, vt2);
  // NODE 3: attention (in-place q -> o in qh)
  attn_all<<<dim3(16, 4, 16), 256, 0, stream>>>(qh, kv1h, kv2h, vt1, vt2);
  // NODE 4: output projection + bias
  gemm_proj<<<512, 256, 0, stream>>>(qh, wf + 3 * 65536, proj_b, out);
}